// Round 1
// baseline (528.661 us; speedup 1.0000x reference)
//
#include <hip/hip_runtime.h>
#include <hip/hip_bf16.h>
#include <math.h>
#include <type_traits>

#define AS1 __attribute__((address_space(1)))
#define AS3 __attribute__((address_space(3)))

typedef __bf16  bf16x8 __attribute__((ext_vector_type(8)));
typedef float   f32x4  __attribute__((ext_vector_type(4)));
typedef __hip_bfloat16 bf16;

#define MFMA16x16x32 __builtin_amdgcn_mfma_f32_16x16x32_bf16

__device__ __forceinline__ void gload16(const void* g, void* l) {
  // async global->LDS, 16B per lane; LDS dest = wave-uniform base + lane*16
  __builtin_amdgcn_global_load_lds((const AS1 void*)g, (AS3 void*)l, 16, 0, 0);
}

// ---------------------------------------------------------------- fp32 -> bf16
__global__ __launch_bounds__(256) void f2bf_kernel(const float4* __restrict__ in,
                                                   ushort4* __restrict__ out, int n4) {
  int i = blockIdx.x * 256 + threadIdx.x;
  if (i >= n4) return;
  float4 v = in[i];
  ushort4 o;
  o.x = __builtin_bit_cast(unsigned short, __float2bfloat16(v.x));
  o.y = __builtin_bit_cast(unsigned short, __float2bfloat16(v.y));
  o.z = __builtin_bit_cast(unsigned short, __float2bfloat16(v.z));
  o.w = __builtin_bit_cast(unsigned short, __float2bfloat16(v.w));
  out[i] = o;
}

// ---------------------------------------------------------------- GEMM  C = A * W^T
// A: (M,K) bf16 row-major.  W: (N,K) bf16 row-major.  C: (M,N) OutT row-major.
// M,N multiples of 128; K multiple of 32.  m97 structure: 128x128 tile, BK=32.
template <typename OutT>
__global__ __launch_bounds__(256, 3) void gemm_bt(const bf16* __restrict__ A,
                                                  const bf16* __restrict__ W,
                                                  OutT* __restrict__ Cp,
                                                  int M, int N, int K) {
  __shared__ __align__(16) bf16 As[128 * 32];
  __shared__ __align__(16) bf16 Ws[128 * 32];
  const int t = threadIdx.x;
  const int w = t >> 6, lane = t & 63;
  const int quad = lane >> 4, l16 = lane & 15;
  const int wr = (w >> 1) * 64, wc = (w & 1) * 64;
  const size_t m0 = (size_t)blockIdx.x * 128;
  const size_t n0 = (size_t)blockIdx.y * 128;

  const int rowS = t >> 2;          // 0..63 (staging row)
  const int kch  = (t & 3) * 8;     // bf16 elems within 32-wide K slice

  f32x4 acc[4][4];
#pragma unroll
  for (int i = 0; i < 4; i++)
#pragma unroll
    for (int j = 0; j < 4; j++) acc[i][j] = f32x4{0.f, 0.f, 0.f, 0.f};

  for (int k0 = 0; k0 < K; k0 += 32) {
    __syncthreads();   // previous tile's reads complete
    gload16(A + (m0 + rowS) * K + k0 + kch,        (char*)As + w * 1024);
    gload16(A + (m0 + rowS + 64) * K + k0 + kch,   (char*)As + 4096 + w * 1024);
    gload16(W + (n0 + rowS) * K + k0 + kch,        (char*)Ws + w * 1024);
    gload16(W + (n0 + rowS + 64) * K + k0 + kch,   (char*)Ws + 4096 + w * 1024);
    __syncthreads();   // staging landed (barrier drains vmcnt)

    bf16x8 af[4], bw[4];
#pragma unroll
    for (int i = 0; i < 4; i++)
      af[i] = *(const bf16x8*)(As + (wr + i * 16 + l16) * 32 + quad * 8);
#pragma unroll
    for (int j = 0; j < 4; j++)
      bw[j] = *(const bf16x8*)(Ws + (wc + j * 16 + l16) * 32 + quad * 8);
#pragma unroll
    for (int i = 0; i < 4; i++)
#pragma unroll
      for (int j = 0; j < 4; j++)
        acc[i][j] = MFMA16x16x32(af[i], bw[j], acc[i][j], 0, 0, 0);
  }

  // epilogue: C/D layout col=lane&15, row=quad*4+reg (m89-verified)
#pragma unroll
  for (int i = 0; i < 4; i++)
#pragma unroll
    for (int j = 0; j < 4; j++)
#pragma unroll
      for (int r = 0; r < 4; r++) {
        size_t row = m0 + wr + i * 16 + quad * 4 + r;
        size_t col = n0 + wc + j * 16 + l16;
        float v = acc[i][j][r];
        if constexpr (std::is_same<OutT, float>::value)
          Cp[row * N + col] = v;
        else
          Cp[row * N + col] = __float2bfloat16(v);
      }
}

// ---------------------------------------------------------------- RoPE + RMSNorm
// qraw: (B*T, 2048) bf16; kvraw: (B*T, 4096) bf16; cos/sin: (T,32) fp32
// qn, kn: (B*T, H, 128) bf16.  One wave per (bt, h).
__global__ __launch_bounds__(256) void rope_rms(const bf16* __restrict__ qraw,
                                                const bf16* __restrict__ kvraw,
                                                const float* __restrict__ cosp,
                                                const float* __restrict__ sinp,
                                                bf16* __restrict__ qn,
                                                bf16* __restrict__ kn) {
  const int bt = blockIdx.x;
  const int w = threadIdx.x >> 6, lane = threadIdx.x & 63;
  const int h = blockIdx.y * 4 + w;
  const int tt = bt & 2047;  // T = 2048
  const float c = cosp[tt * 32 + (lane & 31)];
  const float s = sinp[tt * 32 + (lane & 31)];
  const float inv128 = 1.0f / 128.0f;
  const float eps = 1.1920929e-7f;

  // Q
  {
    const bf16* base = qraw + (size_t)bt * 2048 + h * 128;
    float a = (float)base[lane];
    float o = (float)base[64 + lane];
    float partner = __shfl_xor(o, 32);
    float orope = (lane < 32) ? (o * c + partner * s) : (o * c - partner * s);
    float ss = a * a + orope * orope;
#pragma unroll
    for (int off = 1; off < 64; off <<= 1) ss += __shfl_xor(ss, off);
    float rn = rsqrtf(ss * inv128 + eps);
    bf16* outp = qn + ((size_t)bt * 16 + h) * 128;
    outp[lane] = __float2bfloat16(a * rn);
    outp[64 + lane] = __float2bfloat16(orope * rn);
  }
  // K
  {
    const bf16* base = kvraw + (size_t)bt * 4096 + h * 256;
    float a = (float)base[lane];
    float o = (float)base[64 + lane];
    float partner = __shfl_xor(o, 32);
    float orope = (lane < 32) ? (o * c + partner * s) : (o * c - partner * s);
    float ss = a * a + orope * orope;
#pragma unroll
    for (int off = 1; off < 64; off <<= 1) ss += __shfl_xor(ss, off);
    float rn = rsqrtf(ss * inv128 + eps);
    bf16* outp = kn + ((size_t)bt * 16 + h) * 128;
    outp[lane] = __float2bfloat16(a * rn);
    outp[64 + lane] = __float2bfloat16(orope * rn);
  }
}

// ---------------------------------------------------------------- V transpose
// kvraw (B,T,H,256) [v at 128..255]  ->  vT (B,H,128,T)
__global__ __launch_bounds__(256) void vtrans(const bf16* __restrict__ kvraw,
                                              bf16* __restrict__ vT) {
  __shared__ __align__(16) bf16 tile[64][72];
  const int b = blockIdx.z >> 4, h = blockIdx.z & 15;
  const int t0 = blockIdx.x * 64, d0 = blockIdx.y * 64;
  const int tr = threadIdx.x >> 2;
  const int cc = (threadIdx.x & 3) << 4;  // 16-elem chunk

  const bf16* src = kvraw + ((size_t)(b * 2048 + t0 + tr)) * 4096 + h * 256 + 128 + d0 + cc;
  *(uint4*)&tile[tr][cc]     = *(const uint4*)(src);
  *(uint4*)&tile[tr][cc + 8] = *(const uint4*)(src + 8);
  __syncthreads();

  __align__(16) bf16 tmp[16];
#pragma unroll
  for (int j = 0; j < 16; j++) tmp[j] = tile[cc + j][tr];
  bf16* dst = vT + ((size_t)blockIdx.z * 128 + d0 + tr) * 2048 + t0 + cc;
  *(uint4*)dst       = *(const uint4*)&tmp[0];
  *(uint4*)(dst + 8) = *(const uint4*)&tmp[8];
}

// ---------------------------------------------------------------- flash attention
// qn,kn: (B,T,H,128) bf16; vT: (B,H,128,T) bf16; y: (B,T,2048) bf16
// block = 64 q-rows (4 waves x 16), KV tiles of 64, causal, online softmax.
__global__ __launch_bounds__(256, 3) void attn_kernel(const bf16* __restrict__ qn,
                                                      const bf16* __restrict__ kn,
                                                      const bf16* __restrict__ vT,
                                                      bf16* __restrict__ y) {
  __shared__ __align__(16) bf16 Ks[64 * 128];   // [s][d], chunk-XOR-swizzled
  __shared__ __align__(16) bf16 Vs[128 * 64];   // [d][s], chunk-XOR-swizzled
  __shared__ __align__(16) bf16 Ps[4 * 16 * 72];// per-wave P, stride 72 (bank-safe)
  const int t = threadIdx.x, w = t >> 6, lane = t & 63;
  const int quad = lane >> 4, l16 = lane & 15;
  const int xb = (int)gridDim.x - 1 - (int)blockIdx.x;  // big blocks first
  const int q0 = xb * 64;
  const int h = blockIdx.y, b = blockIdx.z;
  const int T_ = 2048, H_ = 16;

  bf16x8 qf[4];
  {
    const bf16* qbase = qn + ((size_t)(b * T_ + q0 + w * 16 + l16) * H_ + h) * 128;
#pragma unroll
    for (int ks = 0; ks < 4; ks++) qf[ks] = *(const bf16x8*)(qbase + ks * 32 + quad * 8);
  }
  f32x4 yacc[8];
#pragma unroll
  for (int i = 0; i < 8; i++) yacc[i] = f32x4{0.f, 0.f, 0.f, 0.f};
  float mrow[4] = {-INFINITY, -INFINITY, -INFINITY, -INFINITY};
  float lrow[4] = {0.f, 0.f, 0.f, 0.f};
  const float scale = 0.08838834764831845f;  // 1/sqrt(128)
  const int ntiles = xb + 1;

  for (int it = 0; it < ntiles; ++it) {
    const int s0 = it * 64;
    __syncthreads();
    // stage K tile (rows 256B = 16 chunks, swizzle c^=(s&7))
#pragma unroll
    for (int is = 0; is < 4; ++is) {
      int srow = is * 16 + w * 4 + quad;
      int cg = l16 ^ (srow & 7);
      gload16(kn + ((size_t)(b * T_ + s0 + srow) * H_ + h) * 128 + cg * 8,
              (char*)Ks + is * 4096 + w * 1024);
    }
    // stage V tile (rows 128B = 8 chunks, swizzle c^=(d&7))
#pragma unroll
    for (int is = 0; is < 4; ++is) {
      int drow = is * 32 + w * 8 + (lane >> 3);
      int cg = (lane & 7) ^ (drow & 7);
      gload16(vT + ((size_t)(b * H_ + h) * 128 + drow) * T_ + s0 + cg * 8,
              (char*)Vs + is * 4096 + w * 1024);
    }
    __syncthreads();

    // S = Q K^T
    f32x4 sacc[4];
#pragma unroll
    for (int cg = 0; cg < 4; cg++) sacc[cg] = f32x4{0.f, 0.f, 0.f, 0.f};
#pragma unroll
    for (int cg = 0; cg < 4; ++cg) {
      const int srow = cg * 16 + l16;
#pragma unroll
      for (int ks = 0; ks < 4; ++ks) {
        int pos = (ks * 4 + quad) ^ (srow & 7);
        bf16x8 kf = *(const bf16x8*)(Ks + srow * 128 + pos * 8);
        sacc[cg] = MFMA16x16x32(qf[ks], kf, sacc[cg], 0, 0, 0);
      }
    }

    // online softmax (rows live in quad groups: row = quad*4 + r)
    const bool diag = (it == ntiles - 1);
    float p[4][4];
    float mt[4] = {-INFINITY, -INFINITY, -INFINITY, -INFINITY};
#pragma unroll
    for (int cg = 0; cg < 4; ++cg)
#pragma unroll
      for (int r = 0; r < 4; ++r) {
        float sv = sacc[cg][r] * scale;
        if (diag && (cg * 16 + l16 > w * 16 + quad * 4 + r)) sv = -INFINITY;
        p[cg][r] = sv;
        mt[r] = fmaxf(mt[r], sv);
      }
#pragma unroll
    for (int off = 1; off < 16; off <<= 1)
#pragma unroll
      for (int r = 0; r < 4; r++) mt[r] = fmaxf(mt[r], __shfl_xor(mt[r], off));
    float alpha[4];
    float rs[4] = {0.f, 0.f, 0.f, 0.f};
#pragma unroll
    for (int r = 0; r < 4; r++) {
      float mn = fmaxf(mrow[r], mt[r]);
      alpha[r] = __expf(mrow[r] - mn);
      mrow[r] = mn;
    }
#pragma unroll
    for (int cg = 0; cg < 4; cg++)
#pragma unroll
      for (int r = 0; r < 4; r++) {
        float e = __expf(p[cg][r] - mrow[r]);
        p[cg][r] = e;
        rs[r] += e;
      }
#pragma unroll
    for (int off = 1; off < 16; off <<= 1)
#pragma unroll
      for (int r = 0; r < 4; r++) rs[r] += __shfl_xor(rs[r], off);
#pragma unroll
    for (int r = 0; r < 4; r++) lrow[r] = lrow[r] * alpha[r] + rs[r];
#pragma unroll
    for (int dg = 0; dg < 8; dg++) {
      f32x4 v = yacc[dg];
#pragma unroll
      for (int r = 0; r < 4; r++) v[r] *= alpha[r];
      yacc[dg] = v;
    }

    // P: C-layout -> LDS -> A-layout (per-wave region, wave-internal in-order DS)
#pragma unroll
    for (int cg = 0; cg < 4; cg++)
#pragma unroll
      for (int r = 0; r < 4; r++)
        Ps[w * 1152 + (quad * 4 + r) * 72 + cg * 16 + l16] = __float2bfloat16(p[cg][r]);
    __asm__ volatile("s_waitcnt lgkmcnt(0)" ::: "memory");

    bf16x8 pf[2];
#pragma unroll
    for (int k2 = 0; k2 < 2; k2++)
      pf[k2] = *(const bf16x8*)(Ps + w * 1152 + l16 * 72 + k2 * 32 + quad * 8);
#pragma unroll
    for (int dg = 0; dg < 8; dg++) {
      const int drow = dg * 16 + l16;
#pragma unroll
      for (int k2 = 0; k2 < 2; k2++) {
        int pos = (k2 * 4 + quad) ^ (drow & 7);
        bf16x8 vf = *(const bf16x8*)(Vs + drow * 64 + pos * 8);
        yacc[dg] = MFMA16x16x32(pf[k2], vf, yacc[dg], 0, 0, 0);
      }
    }
  }

  // epilogue
#pragma unroll
  for (int r = 0; r < 4; r++) {
    float inv = 1.0f / lrow[r];
    size_t qrow = (size_t)(b * T_ + q0 + w * 16 + quad * 4 + r);
    bf16* outp = y + qrow * 2048 + h * 128;
#pragma unroll
    for (int dg = 0; dg < 8; dg++)
      outp[dg * 16 + l16] = __float2bfloat16(yacc[dg][r] * inv);
  }
}

// ---------------------------------------------------------------- launcher
extern "C" void kernel_launch(void* const* d_in, const int* in_sizes, int n_in,
                              void* d_out, int out_size, void* d_ws, size_t ws_size,
                              hipStream_t stream) {
  (void)in_sizes; (void)n_in; (void)out_size; (void)ws_size;
  const float* x    = (const float*)d_in[0];
  const float* cosp = (const float*)d_in[1];
  const float* sinp = (const float*)d_in[2];
  const float* wqd  = (const float*)d_in[3];
  const float* wqu  = (const float*)d_in[4];
  const float* wkvd = (const float*)d_in[5];
  const float* wkvu = (const float*)d_in[6];
  const float* wo   = (const float*)d_in[7];
  float* out = (float*)d_out;

  char* ws = (char*)d_ws;
  size_t off = 0;
  auto alloc = [&](size_t elems) { bf16* p = (bf16*)(ws + off); off += elems * 2; return p; };
  bf16* xb     = alloc((size_t)4096 * 2048);
  bf16* wqdB   = alloc((size_t)1536 * 2048);
  bf16* wquB   = alloc((size_t)2048 * 1536);
  bf16* wkvdB  = alloc((size_t)512 * 2048);
  bf16* wkvuB  = alloc((size_t)4096 * 512);
  bf16* woB    = alloc((size_t)2048 * 2048);
  bf16* qdown  = alloc((size_t)4096 * 1536);
  bf16* kvdown = alloc((size_t)4096 * 512);
  bf16* qraw   = alloc((size_t)4096 * 2048);
  bf16* kvraw  = alloc((size_t)4096 * 4096);
  bf16* qnb    = alloc((size_t)4096 * 16 * 128);
  bf16* knb    = alloc((size_t)4096 * 16 * 128);
  bf16* vTb    = alloc((size_t)2 * 16 * 128 * 2048);
  bf16* yb     = alloc((size_t)4096 * 2048);

  auto conv = [&](const float* src, bf16* dst, size_t n) {
    f2bf_kernel<<<dim3((unsigned)(n / 1024)), dim3(256), 0, stream>>>(
        (const float4*)src, (ushort4*)dst, (int)(n / 4));
  };
  conv(x,    xb,    (size_t)4096 * 2048);
  conv(wqd,  wqdB,  (size_t)1536 * 2048);
  conv(wqu,  wquB,  (size_t)2048 * 1536);
  conv(wkvd, wkvdB, (size_t)512 * 2048);
  conv(wkvu, wkvuB, (size_t)4096 * 512);
  conv(wo,   woB,   (size_t)2048 * 2048);

  gemm_bt<bf16><<<dim3(32, 12), 256, 0, stream>>>(xb, wqdB, qdown, 4096, 1536, 2048);
  gemm_bt<bf16><<<dim3(32, 4),  256, 0, stream>>>(xb, wkvdB, kvdown, 4096, 512, 2048);
  gemm_bt<bf16><<<dim3(32, 16), 256, 0, stream>>>(qdown, wquB, qraw, 4096, 2048, 1536);
  gemm_bt<bf16><<<dim3(32, 32), 256, 0, stream>>>(kvdown, wkvuB, kvraw, 4096, 4096, 512);
  rope_rms<<<dim3(4096, 4), 256, 0, stream>>>(qraw, kvraw, cosp, sinp, qnb, knb);
  vtrans<<<dim3(32, 2, 32), 256, 0, stream>>>(kvraw, vTb);
  attn_kernel<<<dim3(32, 16, 2), 256, 0, stream>>>(qnb, knb, vTb, yb);
  gemm_bt<float><<<dim3(32, 16), 256, 0, stream>>>(yb, woB, out, 4096, 2048, 2048);
}

// Round 2
// 416.862 us; speedup vs baseline: 1.2682x; 1.2682x over previous
//
#include <hip/hip_runtime.h>
#include <hip/hip_bf16.h>
#include <math.h>
#include <type_traits>

#define AS1 __attribute__((address_space(1)))
#define AS3 __attribute__((address_space(3)))

typedef __bf16  bf16x8 __attribute__((ext_vector_type(8)));
typedef float   f32x4  __attribute__((ext_vector_type(4)));
typedef __hip_bfloat16 bf16;

#define MFMA16x16x32 __builtin_amdgcn_mfma_f32_16x16x32_bf16

__device__ __forceinline__ void gload16(const void* g, void* l) {
  // async global->LDS, 16B per lane; LDS dest = wave-uniform base + lane*16
  __builtin_amdgcn_global_load_lds((const AS1 void*)g, (AS3 void*)l, 16, 0, 0);
}

// ---------------------------------------------------------------- fp32 -> bf16
__global__ __launch_bounds__(256) void f2bf_kernel(const float4* __restrict__ in,
                                                   ushort4* __restrict__ out, int n4) {
  int i = blockIdx.x * 256 + threadIdx.x;
  if (i >= n4) return;
  float4 v = in[i];
  ushort4 o;
  o.x = __builtin_bit_cast(unsigned short, __float2bfloat16(v.x));
  o.y = __builtin_bit_cast(unsigned short, __float2bfloat16(v.y));
  o.z = __builtin_bit_cast(unsigned short, __float2bfloat16(v.z));
  o.w = __builtin_bit_cast(unsigned short, __float2bfloat16(v.w));
  out[i] = o;
}

// ---------------------------------------------------------------- GEMM  C = A * W^T
// A: (M,K) bf16 row-major.  W: (N,K) bf16 row-major.  C: (M,N) OutT row-major.
// M,N multiples of 128; K multiple of 32.  m97 structure: 128x128 tile, BK=32.
template <typename OutT>
__global__ __launch_bounds__(256, 3) void gemm_bt(const bf16* __restrict__ A,
                                                  const bf16* __restrict__ W,
                                                  OutT* __restrict__ Cp,
                                                  int M, int N, int K) {
  __shared__ __align__(16) bf16 As[128 * 32];
  __shared__ __align__(16) bf16 Ws[128 * 32];
  const int t = threadIdx.x;
  const int w = t >> 6, lane = t & 63;
  const int quad = lane >> 4, l16 = lane & 15;
  const int wr = (w >> 1) * 64, wc = (w & 1) * 64;
  const size_t m0 = (size_t)blockIdx.x * 128;
  const size_t n0 = (size_t)blockIdx.y * 128;

  const int rowS = t >> 2;          // 0..63 (staging row)
  const int kch  = (t & 3) * 8;     // bf16 elems within 32-wide K slice

  f32x4 acc[4][4];
#pragma unroll
  for (int i = 0; i < 4; i++)
#pragma unroll
    for (int j = 0; j < 4; j++) acc[i][j] = f32x4{0.f, 0.f, 0.f, 0.f};

  for (int k0 = 0; k0 < K; k0 += 32) {
    __syncthreads();   // previous tile's reads complete
    gload16(A + (m0 + rowS) * K + k0 + kch,        (char*)As + w * 1024);
    gload16(A + (m0 + rowS + 64) * K + k0 + kch,   (char*)As + 4096 + w * 1024);
    gload16(W + (n0 + rowS) * K + k0 + kch,        (char*)Ws + w * 1024);
    gload16(W + (n0 + rowS + 64) * K + k0 + kch,   (char*)Ws + 4096 + w * 1024);
    __syncthreads();   // staging landed (barrier drains vmcnt)

    bf16x8 af[4], bw[4];
#pragma unroll
    for (int i = 0; i < 4; i++)
      af[i] = *(const bf16x8*)(As + (wr + i * 16 + l16) * 32 + quad * 8);
#pragma unroll
    for (int j = 0; j < 4; j++)
      bw[j] = *(const bf16x8*)(Ws + (wc + j * 16 + l16) * 32 + quad * 8);
#pragma unroll
    for (int i = 0; i < 4; i++)
#pragma unroll
      for (int j = 0; j < 4; j++)
        acc[i][j] = MFMA16x16x32(af[i], bw[j], acc[i][j], 0, 0, 0);
  }

  // epilogue: C/D layout col=lane&15, row=quad*4+reg (m89-verified)
#pragma unroll
  for (int i = 0; i < 4; i++)
#pragma unroll
    for (int j = 0; j < 4; j++)
#pragma unroll
      for (int r = 0; r < 4; r++) {
        size_t row = m0 + wr + i * 16 + quad * 4 + r;
        size_t col = n0 + wc + j * 16 + l16;
        float v = acc[i][j][r];
        if constexpr (std::is_same<OutT, float>::value)
          Cp[row * N + col] = v;
        else
          Cp[row * N + col] = __float2bfloat16(v);
      }
}

// ---------------------------------------------------------------- RoPE + RMSNorm
__global__ __launch_bounds__(256) void rope_rms(const bf16* __restrict__ qraw,
                                                const bf16* __restrict__ kvraw,
                                                const float* __restrict__ cosp,
                                                const float* __restrict__ sinp,
                                                bf16* __restrict__ qn,
                                                bf16* __restrict__ kn) {
  const int bt = blockIdx.x;
  const int w = threadIdx.x >> 6, lane = threadIdx.x & 63;
  const int h = blockIdx.y * 4 + w;
  const int tt = bt & 2047;  // T = 2048
  const float c = cosp[tt * 32 + (lane & 31)];
  const float s = sinp[tt * 32 + (lane & 31)];
  const float inv128 = 1.0f / 128.0f;
  const float eps = 1.1920929e-7f;

  // Q
  {
    const bf16* base = qraw + (size_t)bt * 2048 + h * 128;
    float a = (float)base[lane];
    float o = (float)base[64 + lane];
    float partner = __shfl_xor(o, 32);
    float orope = (lane < 32) ? (o * c + partner * s) : (o * c - partner * s);
    float ss = a * a + orope * orope;
#pragma unroll
    for (int off = 1; off < 64; off <<= 1) ss += __shfl_xor(ss, off);
    float rn = rsqrtf(ss * inv128 + eps);
    bf16* outp = qn + ((size_t)bt * 16 + h) * 128;
    outp[lane] = __float2bfloat16(a * rn);
    outp[64 + lane] = __float2bfloat16(orope * rn);
  }
  // K
  {
    const bf16* base = kvraw + (size_t)bt * 4096 + h * 256;
    float a = (float)base[lane];
    float o = (float)base[64 + lane];
    float partner = __shfl_xor(o, 32);
    float orope = (lane < 32) ? (o * c + partner * s) : (o * c - partner * s);
    float ss = a * a + orope * orope;
#pragma unroll
    for (int off = 1; off < 64; off <<= 1) ss += __shfl_xor(ss, off);
    float rn = rsqrtf(ss * inv128 + eps);
    bf16* outp = kn + ((size_t)bt * 16 + h) * 128;
    outp[lane] = __float2bfloat16(a * rn);
    outp[64 + lane] = __float2bfloat16(orope * rn);
  }
}

// ---------------------------------------------------------------- V transpose
// kvraw (B,T,H,256) [v at 128..255]  ->  vT (B,H,128,T)
__global__ __launch_bounds__(256) void vtrans(const bf16* __restrict__ kvraw,
                                              bf16* __restrict__ vT) {
  __shared__ __align__(16) bf16 tile[64][72];
  const int b = blockIdx.z >> 4, h = blockIdx.z & 15;
  const int t0 = blockIdx.x * 64, d0 = blockIdx.y * 64;
  const int tr = threadIdx.x >> 2;
  const int cc = (threadIdx.x & 3) << 4;  // 16-elem chunk

  const bf16* src = kvraw + ((size_t)(b * 2048 + t0 + tr)) * 4096 + h * 256 + 128 + d0 + cc;
  *(uint4*)&tile[tr][cc]     = *(const uint4*)(src);
  *(uint4*)&tile[tr][cc + 8] = *(const uint4*)(src + 8);
  __syncthreads();

  __align__(16) bf16 tmp[16];
#pragma unroll
  for (int j = 0; j < 16; j++) tmp[j] = tile[cc + j][tr];
  bf16* dst = vT + ((size_t)blockIdx.z * 128 + d0 + tr) * 2048 + t0 + cc;
  *(uint4*)dst       = *(const uint4*)&tmp[0];
  *(uint4*)(dst + 8) = *(const uint4*)&tmp[8];
}

// ---------------------------------------------------------------- flash attention
// qn,kn: (B,T,H,128) bf16; vT: (B,H,128,T) bf16; y: (B,T,2048) bf16
// block = 64 q-rows (4 waves x 16), KV tiles of 64, causal.
// FIXED-MAX softmax: q,k are unit-RMS so |q.k|*scale <= sqrt(128) < 12.
// p = 2^(s*scale*log2e - 12*log2e); no in-loop reductions, l summed in epilogue.
// grid: x = b*16+h (32), y: qchunk = 31-y (big blocks first; decorrelates
// work from linear-index mod 256 -> balanced CU load).
__global__ __launch_bounds__(256, 3) void attn_kernel(const bf16* __restrict__ qn,
                                                      const bf16* __restrict__ kn,
                                                      const bf16* __restrict__ vT,
                                                      bf16* __restrict__ y) {
  __shared__ __align__(16) bf16 Ks[64 * 128];   // [s][d], chunk-XOR-swizzled
  __shared__ __align__(16) bf16 Vs[128 * 64];   // [d][s], chunk-XOR-swizzled
  __shared__ __align__(16) bf16 Ps[4 * 16 * 72];// per-wave P, stride 72 (bank-safe)
  const int t = threadIdx.x, w = t >> 6, lane = t & 63;
  const int quad = lane >> 4, l16 = lane & 15;
  const int b = blockIdx.x >> 4, h = blockIdx.x & 15;
  const int xb = 31 - (int)blockIdx.y;          // big blocks first
  const int q0 = xb * 64;
  const int T_ = 2048, H_ = 16;

  bf16x8 qf[4];
  {
    const bf16* qbase = qn + ((size_t)(b * T_ + q0 + w * 16 + l16) * H_ + h) * 128;
#pragma unroll
    for (int ks = 0; ks < 4; ks++) qf[ks] = *(const bf16x8*)(qbase + ks * 32 + quad * 8);
  }
  f32x4 yacc[8];
#pragma unroll
  for (int i = 0; i < 8; i++) yacc[i] = f32x4{0.f, 0.f, 0.f, 0.f};
  float lrow[4] = {0.f, 0.f, 0.f, 0.f};
  // p = exp2(sacc * K1 + K2) = e^(sacc/sqrt(128) - 12)
  const float K1 = 0.08838834764831845f * 1.4426950408889634f;
  const float K2 = -12.0f * 1.4426950408889634f;
  const int ntiles = xb + 1;

  for (int it = 0; it < ntiles; ++it) {
    const int s0 = it * 64;
    __syncthreads();
    // stage K tile (rows 256B = 16 chunks, swizzle c^=(s&7))
#pragma unroll
    for (int is = 0; is < 4; ++is) {
      int srow = is * 16 + w * 4 + quad;
      int cg = l16 ^ (srow & 7);
      gload16(kn + ((size_t)(b * T_ + s0 + srow) * H_ + h) * 128 + cg * 8,
              (char*)Ks + is * 4096 + w * 1024);
    }
    // stage V tile (rows 128B = 8 chunks, swizzle c^=(d&7))
#pragma unroll
    for (int is = 0; is < 4; ++is) {
      int drow = is * 32 + w * 8 + (lane >> 3);
      int cg = (lane & 7) ^ (drow & 7);
      gload16(vT + ((size_t)(b * H_ + h) * 128 + drow) * T_ + s0 + cg * 8,
              (char*)Vs + is * 4096 + w * 1024);
    }
    __syncthreads();

    // S = Q K^T
    f32x4 sacc[4];
#pragma unroll
    for (int cg = 0; cg < 4; cg++) sacc[cg] = f32x4{0.f, 0.f, 0.f, 0.f};
#pragma unroll
    for (int cg = 0; cg < 4; ++cg) {
      const int srow = cg * 16 + l16;
#pragma unroll
      for (int ks = 0; ks < 4; ++ks) {
        int pos = (ks * 4 + quad) ^ (srow & 7);
        bf16x8 kf = *(const bf16x8*)(Ks + srow * 128 + pos * 8);
        sacc[cg] = MFMA16x16x32(qf[ks], kf, sacc[cg], 0, 0, 0);
      }
    }

    // fixed-max softmax: p = exp2(s*K1 + K2); accumulate per-lane partial l
    const bool diag = (it == ntiles - 1);
    float p[4][4];
#pragma unroll
    for (int cg = 0; cg < 4; ++cg)
#pragma unroll
      for (int r = 0; r < 4; ++r) {
        float e;
        if (diag && (cg * 16 + l16 > w * 16 + quad * 4 + r))
          e = 0.0f;
        else
          e = exp2f(fmaf(sacc[cg][r], K1, K2));
        p[cg][r] = e;
        lrow[r] += e;
      }

    // P: C-layout -> LDS -> A-layout (per-wave region, wave-internal in-order DS)
#pragma unroll
    for (int cg = 0; cg < 4; cg++)
#pragma unroll
      for (int r = 0; r < 4; r++)
        Ps[w * 1152 + (quad * 4 + r) * 72 + cg * 16 + l16] = __float2bfloat16(p[cg][r]);
    __asm__ volatile("s_waitcnt lgkmcnt(0)" ::: "memory");

    bf16x8 pf[2];
#pragma unroll
    for (int k2 = 0; k2 < 2; k2++)
      pf[k2] = *(const bf16x8*)(Ps + w * 1152 + l16 * 72 + k2 * 32 + quad * 8);
#pragma unroll
    for (int dg = 0; dg < 8; dg++) {
      const int drow = dg * 16 + l16;
#pragma unroll
      for (int k2 = 0; k2 < 2; k2++) {
        int pos = (k2 * 4 + quad) ^ (drow & 7);
        bf16x8 vf = *(const bf16x8*)(Vs + drow * 64 + pos * 8);
        yacc[dg] = MFMA16x16x32(pf[k2], vf, yacc[dg], 0, 0, 0);
      }
    }
  }

  // epilogue: reduce per-lane l partials across the 16 cols once, then scale
#pragma unroll
  for (int off = 1; off < 16; off <<= 1)
#pragma unroll
    for (int r = 0; r < 4; r++) lrow[r] += __shfl_xor(lrow[r], off);
#pragma unroll
  for (int r = 0; r < 4; r++) {
    float inv = 1.0f / lrow[r];
    size_t qrow = (size_t)(b * T_ + q0 + w * 16 + quad * 4 + r);
    bf16* outp = y + qrow * 2048 + h * 128;
#pragma unroll
    for (int dg = 0; dg < 8; dg++)
      outp[dg * 16 + l16] = __float2bfloat16(yacc[dg][r] * inv);
  }
}

// ---------------------------------------------------------------- launcher
extern "C" void kernel_launch(void* const* d_in, const int* in_sizes, int n_in,
                              void* d_out, int out_size, void* d_ws, size_t ws_size,
                              hipStream_t stream) {
  (void)in_sizes; (void)n_in; (void)out_size; (void)ws_size;
  const float* x    = (const float*)d_in[0];
  const float* cosp = (const float*)d_in[1];
  const float* sinp = (const float*)d_in[2];
  const float* wqd  = (const float*)d_in[3];
  const float* wqu  = (const float*)d_in[4];
  const float* wkvd = (const float*)d_in[5];
  const float* wkvu = (const float*)d_in[6];
  const float* wo   = (const float*)d_in[7];
  float* out = (float*)d_out;

  char* ws = (char*)d_ws;
  size_t off = 0;
  auto alloc = [&](size_t elems) { bf16* p = (bf16*)(ws + off); off += elems * 2; return p; };
  bf16* xb     = alloc((size_t)4096 * 2048);
  bf16* wqdB   = alloc((size_t)1536 * 2048);
  bf16* wquB   = alloc((size_t)2048 * 1536);
  bf16* wkvdB  = alloc((size_t)512 * 2048);
  bf16* wkvuB  = alloc((size_t)4096 * 512);
  bf16* woB    = alloc((size_t)2048 * 2048);
  bf16* qdown  = alloc((size_t)4096 * 1536);
  bf16* kvdown = alloc((size_t)4096 * 512);
  bf16* qraw   = alloc((size_t)4096 * 2048);
  bf16* kvraw  = alloc((size_t)4096 * 4096);
  bf16* qnb    = alloc((size_t)4096 * 16 * 128);
  bf16* knb    = alloc((size_t)4096 * 16 * 128);
  bf16* vTb    = alloc((size_t)2 * 16 * 128 * 2048);
  bf16* yb     = alloc((size_t)4096 * 2048);

  auto conv = [&](const float* src, bf16* dst, size_t n) {
    f2bf_kernel<<<dim3((unsigned)(n / 1024)), dim3(256), 0, stream>>>(
        (const float4*)src, (ushort4*)dst, (int)(n / 4));
  };
  conv(x,    xb,    (size_t)4096 * 2048);
  conv(wqd,  wqdB,  (size_t)1536 * 2048);
  conv(wqu,  wquB,  (size_t)2048 * 1536);
  conv(wkvd, wkvdB, (size_t)512 * 2048);
  conv(wkvu, wkvuB, (size_t)4096 * 512);
  conv(wo,   woB,   (size_t)2048 * 2048);

  gemm_bt<bf16><<<dim3(32, 12), 256, 0, stream>>>(xb, wqdB, qdown, 4096, 1536, 2048);
  gemm_bt<bf16><<<dim3(32, 4),  256, 0, stream>>>(xb, wkvdB, kvdown, 4096, 512, 2048);
  gemm_bt<bf16><<<dim3(32, 16), 256, 0, stream>>>(qdown, wquB, qraw, 4096, 2048, 1536);
  gemm_bt<bf16><<<dim3(32, 32), 256, 0, stream>>>(kvdown, wkvuB, kvraw, 4096, 4096, 512);
  rope_rms<<<dim3(4096, 4), 256, 0, stream>>>(qraw, kvraw, cosp, sinp, qnb, knb);
  vtrans<<<dim3(32, 2, 32), 256, 0, stream>>>(kvraw, vTb);
  attn_kernel<<<dim3(32, 32), 256, 0, stream>>>(qnb, knb, vTb, yb);
  gemm_bt<float><<<dim3(32, 16), 256, 0, stream>>>(yb, woB, out, 4096, 2048, 2048);
}

// Round 3
// 391.549 us; speedup vs baseline: 1.3502x; 1.0646x over previous
//
#include <hip/hip_runtime.h>
#include <hip/hip_bf16.h>
#include <math.h>
#include <type_traits>

#define AS1 __attribute__((address_space(1)))
#define AS3 __attribute__((address_space(3)))

typedef __bf16  bf16x8 __attribute__((ext_vector_type(8)));
typedef float   f32x4  __attribute__((ext_vector_type(4)));
typedef float   f32x16 __attribute__((ext_vector_type(16)));
typedef __hip_bfloat16 bf16;

#define MFMA16x16x32 __builtin_amdgcn_mfma_f32_16x16x32_bf16
#define MFMA32x32x16 __builtin_amdgcn_mfma_f32_32x32x16_bf16

__device__ __forceinline__ void gload16(const void* g, void* l) {
  // async global->LDS, 16B per lane; LDS dest = wave-uniform base + lane*16
  __builtin_amdgcn_global_load_lds((const AS1 void*)g, (AS3 void*)l, 16, 0, 0);
}

// ---------------------------------------------------------------- fused fp32 -> bf16 casts
struct CastArgs {
  const float4* src[6];
  ushort4* dst[6];
  unsigned bound[6];  // cumulative float4 counts
};

__global__ __launch_bounds__(256) void f2bf_multi(CastArgs a) {
  unsigned i = blockIdx.x * 256 + threadIdx.x;
  if (i >= a.bound[5]) return;
  unsigned lo = 0;
  int s = 0;
#pragma unroll
  for (int k = 0; k < 5; k++) {
    if (i >= a.bound[k]) { s = k + 1; lo = a.bound[k]; }
  }
  unsigned idx = i - lo;
  float4 v = a.src[s][idx];
  ushort4 o;
  o.x = __builtin_bit_cast(unsigned short, __float2bfloat16(v.x));
  o.y = __builtin_bit_cast(unsigned short, __float2bfloat16(v.y));
  o.z = __builtin_bit_cast(unsigned short, __float2bfloat16(v.z));
  o.w = __builtin_bit_cast(unsigned short, __float2bfloat16(v.w));
  a.dst[s][idx] = o;
}

// ---------------------------------------------------------------- GEMM  C = A * W^T
// A: (M,K) bf16, row stride lda.  W: (N,K) bf16 contiguous.  C: (M,N) OutT row-major.
// M,N multiples of 128; K multiple of 32.  m97 structure: 128x128 tile, BK=32.
template <typename OutT>
__global__ __launch_bounds__(256, 3) void gemm_bt(const bf16* __restrict__ A,
                                                  const bf16* __restrict__ W,
                                                  OutT* __restrict__ Cp,
                                                  int M, int N, int K, int lda) {
  __shared__ __align__(16) bf16 As[128 * 32];
  __shared__ __align__(16) bf16 Ws[128 * 32];
  const int t = threadIdx.x;
  const int w = t >> 6, lane = t & 63;
  const int quad = lane >> 4, l16 = lane & 15;
  const int wr = (w >> 1) * 64, wc = (w & 1) * 64;
  const size_t m0 = (size_t)blockIdx.x * 128;
  const size_t n0 = (size_t)blockIdx.y * 128;

  const int rowS = t >> 2;          // 0..63 (staging row)
  const int kch  = (t & 3) * 8;     // bf16 elems within 32-wide K slice

  f32x4 acc[4][4];
#pragma unroll
  for (int i = 0; i < 4; i++)
#pragma unroll
    for (int j = 0; j < 4; j++) acc[i][j] = f32x4{0.f, 0.f, 0.f, 0.f};

  for (int k0 = 0; k0 < K; k0 += 32) {
    __syncthreads();   // previous tile's reads complete
    gload16(A + (m0 + rowS) * (size_t)lda + k0 + kch,      (char*)As + w * 1024);
    gload16(A + (m0 + rowS + 64) * (size_t)lda + k0 + kch, (char*)As + 4096 + w * 1024);
    gload16(W + (n0 + rowS) * (size_t)K + k0 + kch,        (char*)Ws + w * 1024);
    gload16(W + (n0 + rowS + 64) * (size_t)K + k0 + kch,   (char*)Ws + 4096 + w * 1024);
    __syncthreads();   // staging landed (barrier drains vmcnt)

    bf16x8 af[4], bw[4];
#pragma unroll
    for (int i = 0; i < 4; i++)
      af[i] = *(const bf16x8*)(As + (wr + i * 16 + l16) * 32 + quad * 8);
#pragma unroll
    for (int j = 0; j < 4; j++)
      bw[j] = *(const bf16x8*)(Ws + (wc + j * 16 + l16) * 32 + quad * 8);
#pragma unroll
    for (int i = 0; i < 4; i++)
#pragma unroll
      for (int j = 0; j < 4; j++)
        acc[i][j] = MFMA16x16x32(af[i], bw[j], acc[i][j], 0, 0, 0);
  }

  // epilogue: C/D layout col=lane&15, row=quad*4+reg (m89-verified)
#pragma unroll
  for (int i = 0; i < 4; i++)
#pragma unroll
    for (int j = 0; j < 4; j++)
#pragma unroll
      for (int r = 0; r < 4; r++) {
        size_t row = m0 + wr + i * 16 + quad * 4 + r;
        size_t col = n0 + wc + j * 16 + l16;
        float v = acc[i][j][r];
        if constexpr (std::is_same<OutT, float>::value)
          Cp[row * N + col] = v;
        else
          Cp[row * N + col] = __float2bfloat16(v);
      }
}

// ---------------------------------------------------------------- RoPE + RMSNorm
// qraw: (B*T, 2048) bf16; kvraw: (B*T, 4096) bf16; cos/sin: (T,32) fp32
__global__ __launch_bounds__(256) void rope_rms(const bf16* __restrict__ qraw,
                                                const bf16* __restrict__ kvraw,
                                                const float* __restrict__ cosp,
                                                const float* __restrict__ sinp,
                                                bf16* __restrict__ qn,
                                                bf16* __restrict__ kn) {
  const int bt = blockIdx.x;
  const int w = threadIdx.x >> 6, lane = threadIdx.x & 63;
  const int h = blockIdx.y * 4 + w;
  const int tt = bt & 2047;  // T = 2048
  const float c = cosp[tt * 32 + (lane & 31)];
  const float s = sinp[tt * 32 + (lane & 31)];
  const float inv128 = 1.0f / 128.0f;
  const float eps = 1.1920929e-7f;

  // Q
  {
    const bf16* base = qraw + (size_t)bt * 2048 + h * 128;
    float a = (float)base[lane];
    float o = (float)base[64 + lane];
    float partner = __shfl_xor(o, 32);
    float orope = (lane < 32) ? (o * c + partner * s) : (o * c - partner * s);
    float ss = a * a + orope * orope;
#pragma unroll
    for (int off = 1; off < 64; off <<= 1) ss += __shfl_xor(ss, off);
    float rn = rsqrtf(ss * inv128 + eps);
    bf16* outp = qn + ((size_t)bt * 16 + h) * 128;
    outp[lane] = __float2bfloat16(a * rn);
    outp[64 + lane] = __float2bfloat16(orope * rn);
  }
  // K
  {
    const bf16* base = kvraw + (size_t)bt * 4096 + h * 256;
    float a = (float)base[lane];
    float o = (float)base[64 + lane];
    float partner = __shfl_xor(o, 32);
    float orope = (lane < 32) ? (o * c + partner * s) : (o * c - partner * s);
    float ss = a * a + orope * orope;
#pragma unroll
    for (int off = 1; off < 64; off <<= 1) ss += __shfl_xor(ss, off);
    float rn = rsqrtf(ss * inv128 + eps);
    bf16* outp = kn + ((size_t)bt * 16 + h) * 128;
    outp[lane] = __float2bfloat16(a * rn);
    outp[64 + lane] = __float2bfloat16(orope * rn);
  }
}

// ---------------------------------------------------------------- V transpose
// kvraw (B,T,H,256) [v at 128..255]  ->  vT (B,H,128,T)
__global__ __launch_bounds__(256) void vtrans(const bf16* __restrict__ kvraw,
                                              bf16* __restrict__ vT) {
  __shared__ __align__(16) bf16 tile[64][72];
  const int b = blockIdx.z >> 4, h = blockIdx.z & 15;
  const int t0 = blockIdx.x * 64, d0 = blockIdx.y * 64;
  const int tr = threadIdx.x >> 2;
  const int cc = (threadIdx.x & 3) << 4;  // 16-elem chunk

  const bf16* src = kvraw + ((size_t)(b * 2048 + t0 + tr)) * 4096 + h * 256 + 128 + d0 + cc;
  *(uint4*)&tile[tr][cc]     = *(const uint4*)(src);
  *(uint4*)&tile[tr][cc + 8] = *(const uint4*)(src + 8);
  __syncthreads();

  __align__(16) bf16 tmp[16];
#pragma unroll
  for (int j = 0; j < 16; j++) tmp[j] = tile[cc + j][tr];
  bf16* dst = vT + ((size_t)blockIdx.z * 128 + d0 + tr) * 2048 + t0 + cc;
  *(uint4*)dst       = *(const uint4*)&tmp[0];
  *(uint4*)(dst + 8) = *(const uint4*)&tmp[8];
}

// ---------------------------------------------------------------- flash attention
// 128 q-rows/block (4 waves x 32 rows), 64-wide KV tiles, 32x32x16 MFMA.
// Fixed-max softmax (|q.k|*scale <= sqrt(128) < 12): p = exp2(s*K1+K2),
// l = per-lane partial, reduced once in epilogue.
// A-frag (32x32x16): m=lane&31, k=(lane>>5)*8+j.  B-frag: n=lane&31, same k.
// C/D: col=lane&31, row=(reg&3)+8*(reg>>2)+4*(lane>>5)  [m74/m101-verified]
__global__ __launch_bounds__(256, 2) void attn_kernel(const bf16* __restrict__ qn,
                                                      const bf16* __restrict__ kn,
                                                      const bf16* __restrict__ vT,
                                                      bf16* __restrict__ y) {
  __shared__ __align__(16) bf16 Ks[64 * 128];    // [s][k-chunks swizzled]
  __shared__ __align__(16) bf16 Vs[128 * 64];    // [d][s-chunks swizzled]
  __shared__ __align__(16) bf16 Ps[4][32 * 64];  // per-wave P, chunk-swizzled
  const int t = threadIdx.x, w = t >> 6, lane = t & 63;
  const int l32 = lane & 31, hl = lane >> 5;
  const int b = blockIdx.x >> 4, h = blockIdx.x & 15;
  const int yy = blockIdx.y;
  // CU pairing: linear blocks l and l+256 have y and y+8 -> tiles sum = 34 (balanced)
  const int xb = (yy < 8) ? (15 - yy) : (yy - 8);
  const int q0 = xb * 128;
  const int T_ = 2048, H_ = 16;

  // Q preload to registers: wave w owns q-rows q0+w*32 .. +31
  bf16x8 qf[8];
  {
    const bf16* qbase = qn + ((size_t)(b * T_ + q0 + w * 32 + l32) * H_ + h) * 128;
#pragma unroll
    for (int ki = 0; ki < 8; ki++)
      qf[ki] = *(const bf16x8*)(qbase + (ki * 2 + hl) * 8);
  }

  f32x16 yacc[4];
#pragma unroll
  for (int db = 0; db < 4; db++)
#pragma unroll
    for (int i = 0; i < 16; i++) yacc[db][i] = 0.f;
  float lrow[16];
#pragma unroll
  for (int r = 0; r < 16; r++) lrow[r] = 0.f;
  const float K1 = 0.08838834764831845f * 1.4426950408889634f;
  const float K2 = -12.0f * 1.4426950408889634f;
  const int ntiles = 2 * xb + 2;

  for (int it = 0; it < ntiles; ++it) {
    const int s0 = it * 64;
    __syncthreads();
    // stage K tile: 64 rows x 128 (16 chunks/row), swizzle chunk ^= (s&7)
#pragma unroll
    for (int is = 0; is < 4; ++is) {
      int srow = is * 16 + w * 4 + (lane >> 4);
      int cg = (lane & 15) ^ (srow & 7);
      gload16(kn + ((size_t)(b * T_ + s0 + srow) * H_ + h) * 128 + cg * 8,
              (char*)Ks + is * 4096 + w * 1024);
    }
    // stage V tile: 128 rows x 64 (8 chunks/row), swizzle chunk ^= (d&7)
#pragma unroll
    for (int is = 0; is < 4; ++is) {
      int drow = is * 32 + w * 8 + (lane >> 3);
      int cg = (lane & 7) ^ (drow & 7);
      gload16(vT + ((size_t)(b * H_ + h) * 128 + drow) * T_ + s0 + cg * 8,
              (char*)Vs + is * 4096 + w * 1024);
    }
    __syncthreads();

    // S = Q K^T : 2 col-blocks x 8 k-iters
    f32x16 sacc[2];
#pragma unroll
    for (int cb = 0; cb < 2; cb++)
#pragma unroll
      for (int i = 0; i < 16; i++) sacc[cb][i] = 0.f;
#pragma unroll
    for (int cb = 0; cb < 2; ++cb) {
      const int s = cb * 32 + l32;
#pragma unroll
      for (int ki = 0; ki < 8; ++ki) {
        int pos = (ki * 2 + hl) ^ (s & 7);
        bf16x8 kf = *(const bf16x8*)(Ks + s * 128 + pos * 8);
        sacc[cb] = MFMA32x32x16(qf[ki], kf, sacc[cb], 0, 0, 0);
      }
    }

    // fixed-max softmax + store P to per-wave LDS (chunk-swizzled)
    const bool diag = (it >= ntiles - 2);
#pragma unroll
    for (int cb = 0; cb < 2; ++cb) {
      const int sidx = cb * 32 + l32;
      const int sg = s0 + sidx;
#pragma unroll
      for (int r = 0; r < 16; ++r) {
        const int row = (r & 3) + 8 * (r >> 2) + 4 * hl;
        float e;
        if (diag && (sg > q0 + w * 32 + row))
          e = 0.0f;
        else
          e = exp2f(fmaf(sacc[cb][r], K1, K2));
        lrow[r] += e;
        Ps[w][row * 64 + (((sidx >> 3) ^ (row & 7)) << 3) + (sidx & 7)] =
            __float2bfloat16(e);
      }
    }
    __asm__ volatile("s_waitcnt lgkmcnt(0)" ::: "memory");

    // O += P V : A-frag from Ps (m=l32), B-frag from Vs (n=d)
#pragma unroll
    for (int ki = 0; ki < 4; ++ki) {
      int ppos = (ki * 2 + hl) ^ (l32 & 7);
      bf16x8 pf = *(const bf16x8*)(&Ps[w][l32 * 64 + ppos * 8]);
#pragma unroll
      for (int db = 0; db < 4; ++db) {
        int d = db * 32 + l32;
        int vpos = (ki * 2 + hl) ^ (d & 7);
        bf16x8 vf = *(const bf16x8*)(Vs + d * 64 + vpos * 8);
        yacc[db] = MFMA32x32x16(pf, vf, yacc[db], 0, 0, 0);
      }
    }
  }

  // epilogue: reduce l partials across the 32 s-lanes (bit5 preserved), scale, store
#pragma unroll
  for (int r = 0; r < 16; r++) {
#pragma unroll
    for (int off = 1; off < 32; off <<= 1) lrow[r] += __shfl_xor(lrow[r], off);
  }
#pragma unroll
  for (int r = 0; r < 16; r++) {
    const int row = (r & 3) + 8 * (r >> 2) + 4 * hl;
    float inv = 1.0f / lrow[r];
    size_t qrow = (size_t)(b * T_ + q0 + w * 32 + row);
    bf16* outp = y + qrow * 2048 + h * 128;
#pragma unroll
    for (int db = 0; db < 4; db++)
      outp[db * 32 + l32] = __float2bfloat16(yacc[db][r] * inv);
  }
}

// ---------------------------------------------------------------- launcher
extern "C" void kernel_launch(void* const* d_in, const int* in_sizes, int n_in,
                              void* d_out, int out_size, void* d_ws, size_t ws_size,
                              hipStream_t stream) {
  (void)in_sizes; (void)n_in; (void)out_size; (void)ws_size;
  const float* x    = (const float*)d_in[0];
  const float* cosp = (const float*)d_in[1];
  const float* sinp = (const float*)d_in[2];
  const float* wqd  = (const float*)d_in[3];
  const float* wqu  = (const float*)d_in[4];
  const float* wkvd = (const float*)d_in[5];
  const float* wkvu = (const float*)d_in[6];
  const float* wo   = (const float*)d_in[7];
  float* out = (float*)d_out;

  char* ws = (char*)d_ws;
  size_t off = 0;
  auto alloc = [&](size_t elems) { bf16* p = (bf16*)(ws + off); off += elems * 2; return p; };
  bf16* xb      = alloc((size_t)4096 * 2048);
  bf16* wqdB    = alloc((size_t)1536 * 2048);  // wqdB+wkvdB contiguous: fused (2048,2048) W
  bf16* wkvdB   = alloc((size_t)512 * 2048);
  bf16* wquB    = alloc((size_t)2048 * 1536);
  bf16* wkvuB   = alloc((size_t)4096 * 512);
  bf16* woB     = alloc((size_t)2048 * 2048);
  bf16* qkvdown = alloc((size_t)4096 * 2048);  // cols 0..1535 = qdown, 1536..2047 = kvdown
  bf16* qraw    = alloc((size_t)4096 * 2048);
  bf16* kvraw   = alloc((size_t)4096 * 4096);
  bf16* qnb     = alloc((size_t)4096 * 16 * 128);
  bf16* knb     = alloc((size_t)4096 * 16 * 128);
  bf16* vTb     = alloc((size_t)2 * 16 * 128 * 2048);
  bf16* yb      = alloc((size_t)4096 * 2048);

  // one fused cast launch for all six fp32->bf16 conversions
  CastArgs ca;
  const float* srcs[6] = {x, wqd, wkvd, wqu, wkvu, wo};
  bf16* dsts[6]        = {xb, wqdB, wkvdB, wquB, wkvuB, woB};
  size_t cnts[6] = {(size_t)4096 * 2048, (size_t)1536 * 2048, (size_t)512 * 2048,
                    (size_t)2048 * 1536, (size_t)4096 * 512,  (size_t)2048 * 2048};
  unsigned cum = 0;
  for (int i = 0; i < 6; i++) {
    ca.src[i] = (const float4*)srcs[i];
    ca.dst[i] = (ushort4*)dsts[i];
    cum += (unsigned)(cnts[i] / 4);
    ca.bound[i] = cum;
  }
  f2bf_multi<<<dim3((cum + 255) / 256), 256, 0, stream>>>(ca);

  // fused down-proj: (4096 x 2048) = x @ [wq_down; wkv_down]^T
  gemm_bt<bf16><<<dim3(32, 16), 256, 0, stream>>>(xb, wqdB, qkvdown, 4096, 2048, 2048, 2048);
  // up-projections read strided columns of qkvdown
  gemm_bt<bf16><<<dim3(32, 16), 256, 0, stream>>>(qkvdown, wquB, qraw, 4096, 2048, 1536, 2048);
  gemm_bt<bf16><<<dim3(32, 32), 256, 0, stream>>>(qkvdown + 1536, wkvuB, kvraw, 4096, 4096, 512, 2048);
  rope_rms<<<dim3(4096, 4), 256, 0, stream>>>(qraw, kvraw, cosp, sinp, qnb, knb);
  vtrans<<<dim3(32, 2, 32), 256, 0, stream>>>(kvraw, vTb);
  attn_kernel<<<dim3(32, 16), 256, 0, stream>>>(qnb, knb, vTb, yb);
  gemm_bt<float><<<dim3(32, 16), 256, 0, stream>>>(yb, woB, out, 4096, 2048, 2048, 2048);
}